// Round 4
// baseline (581.385 us; speedup 1.0000x reference)
//
#include <hip/hip_runtime.h>

typedef _Float16 f16;
typedef f16 f16x8 __attribute__((ext_vector_type(8)));
typedef f16 f16x4 __attribute__((ext_vector_type(4)));
typedef f16 f16x2 __attribute__((ext_vector_type(2)));
typedef float f32x4 __attribute__((ext_vector_type(4)));

#define MFMA16(a,b,c) __builtin_amdgcn_mfma_f32_16x16x32_f16((a),(b),(c),0,0,0)

static __device__ __forceinline__ f16x8 ld8(const f16* p){ return *(const f16x8*)p; }
static __device__ __forceinline__ float sigm(float x){ return 1.f/(1.f + __expf(-x)); }

// ---------------------------------------------------------------------------
// Weight prep: fold gammas, cast fp16, transpose to N-major (K contiguous).
// Extras: colsums of Wsl/Wss (raw-s gate un-normalization), gamma_z*Wz fused
// vector + its per-head colsum (z-LN fixup).
// ---------------------------------------------------------------------------
__global__ __launch_bounds__(256) void k_prep(
    const float* __restrict__ apb_gamma, const float* __restrict__ apb_Wg, const float* __restrict__ apb_Wskip,
    const float* __restrict__ ct_gamma,  const float* __restrict__ ct_Wg,  const float* __restrict__ ct_Wskip,
    const float* __restrict__ Wq, const float* __restrict__ Wk, const float* __restrict__ Wv, const float* __restrict__ Wgate,
    const float* __restrict__ Wsl, const float* __restrict__ Wss,
    const float* __restrict__ Wa1, const float* __restrict__ Wa2,
    const float* __restrict__ Wo, const float* __restrict__ Wb,
    const float* __restrict__ gamma_z, const float* __restrict__ Wz,
    f16* __restrict__ wA, f16* __restrict__ wC, f16* __restrict__ wQK, f16* __restrict__ wVG,
    f16* __restrict__ wSG, f16* __restrict__ wAB, f16* __restrict__ wO, f16* __restrict__ wBt,
    float* __restrict__ wzg, float* __restrict__ Slv, float* __restrict__ Ssv,
    float* __restrict__ wcs)
{
  const int t0 = blockIdx.x*256 + threadIdx.x;
  const int stride = gridDim.x*256;
  for (int i = t0; i < 256*128; i += stride){
    const int n = i >> 7, k = i & 127;
    const int m = n & 127;
    wA[i]  = (f16)(((n<128) ? apb_Wg[k*128+m] : apb_Wskip[k*128+m]) * apb_gamma[k]);
    wC[i]  = (f16)(((n<128) ? ct_Wg[k*128+m]  : ct_Wskip[k*128+m])  * ct_gamma[k]);
    wQK[i] = (f16)((n<128) ? Wq[k*128+m] : Wk[k*128+m]);
    wVG[i] = (f16)((n<128) ? Wv[k*128+m] : Wgate[k*128+m]);
    wSG[i] = (f16)((n<128) ? Wsl[k*128+m] : Wss[k*128+m]);
  }
  for (int i = t0; i < 512*128; i += stride){
    const int n = i >> 7, k = i & 127;
    wAB[i] = (f16)((n < 256) ? Wa1[k*256 + n] : Wa2[k*256 + (n-256)]);
  }
  for (int i = t0; i < 128*128; i += stride){
    const int n = i >> 7, k = i & 127;
    wO[i] = (f16)Wo[k*128+n];
  }
  for (int i = t0; i < 128*256; i += stride){
    const int n = i >> 8, k = i & 255;
    wBt[i] = (f16)Wb[k*128+n];
  }
  if (t0 < 64) wzg[t0] = gamma_z[t0 & 15] * Wz[(t0 & 15)*4 + (t0 >> 4)];
  if (t0 < 256){
    const int cc = t0 & 127;
    const float* Wp = (t0 >= 128) ? Wss : Wsl;
    float acc = 0.f;
    for (int k = 0; k < 128; k++) acc += Wp[k*128 + cc];
    if (t0 >= 128) Ssv[cc] = acc; else Slv[cc] = acc;
  }
  if (t0 < 4){
    float acc = 0.f;
    for (int cc = 0; cc < 16; cc++) acc += gamma_z[cc]*Wz[cc*4 + t0];
    wcs[t0] = acc;
  }
}

// ---------------------------------------------------------------------------
// MEGA-FUSED pre-attention. 64 rows/block, 256 threads (4 waves).
// Phase 1: LN(a), LN(s) -> LDS + per-row s mean/std.
// Phase 2: dual adaLN per col-tile job; a3 OVERLAYS lan (dead after read).
// Phase 3: QKVG, transition, gates (un-normalized s trick).
// LDS 52 KB -> 3 blocks/CU.
// ---------------------------------------------------------------------------
__global__ __launch_bounds__(256,3) void k_pre(
    const float* __restrict__ A, const float* __restrict__ S,
    const f16* __restrict__ wA, const f16* __restrict__ wC,
    const f16* __restrict__ wQK, const f16* __restrict__ wVG,
    const f16* __restrict__ wSG, const f16* __restrict__ wAB,
    const float* __restrict__ bgA, const float* __restrict__ bgC,
    const float* __restrict__ bq, const float* __restrict__ bsl, const float* __restrict__ bss,
    const float* __restrict__ Slv, const float* __restrict__ Ssv,
    f16* __restrict__ Qo, f16* __restrict__ Ko, f16* __restrict__ Vt, f16* __restrict__ Go,
    f16* __restrict__ T, f16* __restrict__ GL, f16* __restrict__ GS)
{
  __shared__ __attribute__((aligned(16))) f16 lsn[64*136];
  __shared__ __attribute__((aligned(16))) f16 lan[64*136];   // a_n, then a3
  __shared__ __attribute__((aligned(16))) f16 la1[64*136];
  __shared__ float lsm[64], lsd[64];
  const int tid = threadIdx.x;
  const size_t rbase = (size_t)blockIdx.x * 64;

  // ---- Phase 1: LayerNorm ----
  {
    const int row = tid >> 2, part = tid & 3;
    const size_t gr = rbase + row;
    {
      const float* sp = S + gr*128 + part*32;
      float v[32];
      #pragma unroll
      for (int j = 0; j < 8; j++){
        const float4 t4 = ((const float4*)sp)[j];
        v[j*4+0]=t4.x; v[j*4+1]=t4.y; v[j*4+2]=t4.z; v[j*4+3]=t4.w;
      }
      float sm = 0.f, sq = 0.f;
      #pragma unroll
      for (int j = 0; j < 32; j++){ sm += v[j]; sq += v[j]*v[j]; }
      sm += __shfl_xor(sm,1); sq += __shfl_xor(sq,1);
      sm += __shfl_xor(sm,2); sq += __shfl_xor(sq,2);
      const float mean = sm*(1.f/128.f);
      const float var  = sq*(1.f/128.f) - mean*mean;
      const float rstd = rsqrtf(var + 1e-5f);
      if (part == 0){ lsm[row] = mean; lsd[row] = (var + 1e-5f)*rstd; }
      #pragma unroll
      for (int j = 0; j < 4; j++){
        f16x8 o;
        #pragma unroll
        for (int e = 0; e < 8; e++) o[e] = (f16)((v[j*8+e]-mean)*rstd);
        *(f16x8*)&lsn[row*136 + part*32 + j*8] = o;
      }
    }
    {
      const float* ap = A + gr*128 + part*32;
      float v[32];
      #pragma unroll
      for (int j = 0; j < 8; j++){
        const float4 t4 = ((const float4*)ap)[j];
        v[j*4+0]=t4.x; v[j*4+1]=t4.y; v[j*4+2]=t4.z; v[j*4+3]=t4.w;
      }
      float sm = 0.f, sq = 0.f;
      #pragma unroll
      for (int j = 0; j < 32; j++){ sm += v[j]; sq += v[j]*v[j]; }
      sm += __shfl_xor(sm,1); sq += __shfl_xor(sq,1);
      sm += __shfl_xor(sm,2); sq += __shfl_xor(sq,2);
      const float mean = sm*(1.f/128.f);
      const float var  = sq*(1.f/128.f) - mean*mean;
      const float rstd = rsqrtf(var + 1e-5f);
      #pragma unroll
      for (int j = 0; j < 4; j++){
        f16x8 o;
        #pragma unroll
        for (int e = 0; e < 8; e++) o[e] = (f16)((v[j*8+e]-mean)*rstd);
        *(f16x8*)&lan[row*136 + part*32 + j*8] = o;
      }
    }
  }
  __syncthreads();

  const int l = tid & 63, w = tid >> 6;
  const int c = l & 15, q4 = l >> 4;

  // ---- Phase 2: dual adaLN, one job per col-tile (8 jobs) ----
  for (int jj = 0; jj < 2; jj++){
    const int n0 = (jj*4 + w)*16;
    const float bvA = bgA[n0 + c], bvC = bgC[n0 + c];
    f16x8 bA0[4], bA1[4], bC0[4], bC1[4];
    #pragma unroll
    for (int kc = 0; kc < 4; kc++){
      bA0[kc] = ld8(wA + (size_t)(n0 + c)*128 + kc*32 + q4*8);
      bA1[kc] = ld8(wA + (size_t)(128 + n0 + c)*128 + kc*32 + q4*8);
      bC0[kc] = ld8(wC + (size_t)(n0 + c)*128 + kc*32 + q4*8);
      bC1[kc] = ld8(wC + (size_t)(128 + n0 + c)*128 + kc*32 + q4*8);
    }
    for (int mi = 0; mi < 4; mi++){
      f32x4 dA0 = {0,0,0,0}, dA1 = {0,0,0,0}, dC0 = {0,0,0,0}, dC1 = {0,0,0,0};
      #pragma unroll
      for (int kc = 0; kc < 4; kc++){
        const f16x8 av = *(const f16x8*)&lsn[(mi*16 + c)*136 + kc*32 + q4*8];
        dA0 = MFMA16(av, bA0[kc], dA0);
        dA1 = MFMA16(av, bA1[kc], dA1);
        dC0 = MFMA16(av, bC0[kc], dC0);
        dC1 = MFMA16(av, bC1[kc], dC1);
      }
      #pragma unroll
      for (int r = 0; r < 4; r++){
        const int row = mi*16 + q4*4 + r;
        const float anv = (float)lan[row*136 + n0 + c];
        la1[row*136 + n0 + c] = (f16)(sigm(dA0[r] + bvA)*anv + dA1[r]);
        lan[row*136 + n0 + c] = (f16)(sigm(dC0[r] + bvC)*anv + dC1[r]);   // a3 overlays a_n
      }
    }
  }
  __syncthreads();

  // ---- Phase 3a: QKVG from a1 ----
  for (int jj = 0; jj < 2; jj++){
    const int n0 = (jj*4 + w)*16;
    f16x8 bQ[4], bK[4], bV[4], bG[4];
    #pragma unroll
    for (int kc = 0; kc < 4; kc++){
      bQ[kc] = ld8(wQK + (size_t)(n0 + c)*128 + kc*32 + q4*8);
      bK[kc] = ld8(wQK + (size_t)(128 + n0 + c)*128 + kc*32 + q4*8);
      bV[kc] = ld8(wVG + (size_t)(n0 + c)*128 + kc*32 + q4*8);
      bG[kc] = ld8(wVG + (size_t)(128 + n0 + c)*128 + kc*32 + q4*8);
    }
    const float bvq = bq[n0 + c];
    for (int mi = 0; mi < 4; mi++){
      f32x4 dQ = {0,0,0,0}, dK = {0,0,0,0}, dV = {0,0,0,0}, dG = {0,0,0,0};
      #pragma unroll
      for (int kc = 0; kc < 4; kc++){
        const f16x8 av = *(const f16x8*)&la1[(mi*16 + c)*136 + kc*32 + q4*8];
        dQ = MFMA16(av, bQ[kc], dQ);
        dK = MFMA16(av, bK[kc], dK);
        dV = MFMA16(av, bV[kc], dV);
        dG = MFMA16(av, bG[kc], dG);
      }
      #pragma unroll
      for (int r = 0; r < 4; r++){
        const size_t grow = rbase + mi*16 + q4*4 + r;
        Qo[grow*128 + n0 + c] = (f16)((dQ[r] + bvq)*0.17677669529663687f);
        Ko[grow*128 + n0 + c] = (f16)dK[r];
        Go[grow*128 + n0 + c] = (f16)sigm(dG[r]);
      }
      f16x4 vv;
      #pragma unroll
      for (int r = 0; r < 4; r++) vv[r] = (f16)dV[r];
      const int bidx = (int)(rbase >> 14);
      const int ntk  = (int)(rbase & 16383) + mi*16 + q4*4;
      *(f16x4*)(Vt + ((size_t)bidx*128 + n0 + c)*16384 + ntk) = vv;
    }
  }

  // ---- Phase 3b: transition from a3 (in lan) ----
  for (int jj = 0; jj < 4; jj++){
    const int n0t = (jj*4 + w)*16;
    f16x8 b1v[4], b2v[4];
    #pragma unroll
    for (int kc = 0; kc < 4; kc++){
      b1v[kc] = ld8(wAB + (size_t)(n0t + c)*128 + kc*32 + q4*8);
      b2v[kc] = ld8(wAB + (size_t)(256 + n0t + c)*128 + kc*32 + q4*8);
    }
    for (int mi = 0; mi < 4; mi++){
      f32x4 d0 = {0,0,0,0}, d1 = {0,0,0,0};
      #pragma unroll
      for (int kc = 0; kc < 4; kc++){
        const f16x8 av = *(const f16x8*)&lan[(mi*16 + c)*136 + kc*32 + q4*8];
        d0 = MFMA16(av, b1v[kc], d0);
        d1 = MFMA16(av, b2v[kc], d1);
      }
      #pragma unroll
      for (int r = 0; r < 4; r++){
        const size_t grow = rbase + mi*16 + q4*4 + r;
        const float u = d0[r];
        T[grow*256 + n0t + c] = (f16)((u*sigm(u))*d1[r]);
      }
    }
  }

  // ---- Phase 3c: gates from sn (un-normalization trick) ----
  for (int jj = 0; jj < 2; jj++){
    const int n0 = (jj*4 + w)*16;
    f16x8 b0[4], b1[4];
    #pragma unroll
    for (int kc = 0; kc < 4; kc++){
      b0[kc] = ld8(wSG + (size_t)(n0 + c)*128 + kc*32 + q4*8);
      b1[kc] = ld8(wSG + (size_t)(128 + n0 + c)*128 + kc*32 + q4*8);
    }
    const float slc = Slv[n0 + c], ssc = Ssv[n0 + c];
    const float bl = bsl[n0 + c],  bs2 = bss[n0 + c];
    for (int mi = 0; mi < 4; mi++){
      f32x4 d0 = {0,0,0,0}, d1 = {0,0,0,0};
      #pragma unroll
      for (int kc = 0; kc < 4; kc++){
        const f16x8 av = *(const f16x8*)&lsn[(mi*16 + c)*136 + kc*32 + q4*8];
        d0 = MFMA16(av, b0[kc], d0);
        d1 = MFMA16(av, b1[kc], d1);
      }
      #pragma unroll
      for (int r = 0; r < 4; r++){
        const int row = mi*16 + q4*4 + r;
        const size_t grow = rbase + row;
        const float mn = lsm[row], sd = lsd[row];
        GL[grow*128 + n0 + c] = (f16)sigm(d0[r]*sd + mn*slc + bl);
        GS[grow*128 + n0 + c] = (f16)sigm(d1[r]*sd + mn*ssc + bs2);
      }
    }
  }
}

// ---------------------------------------------------------------------------
// Fused attention + OUTPUT PROJECTION. One block per (b, nb); 8 waves.
// Order: QK scores (global frags, overlaps z stream) -> z-bias -> softmax ->
// PV -> o in LDS -> out = gl*((g.o)@Wo) + gs*(t@Wb) -> fp32 store.
// ---------------------------------------------------------------------------
__global__ __launch_bounds__(512,2) void k_attn(const f16* __restrict__ Q, const f16* __restrict__ K,
    const f16* __restrict__ VT, const float* __restrict__ Z, const float* __restrict__ WZG,
    const float* __restrict__ WCS,
    const f16* __restrict__ G, const f16* __restrict__ T,
    const f16* __restrict__ GL, const f16* __restrict__ GS,
    const f16* __restrict__ Wot, const f16* __restrict__ Wbt,
    float* __restrict__ out)
{
  __shared__ __attribute__((aligned(16))) f16 upb[17408];   // bias[4][32][132] then P[8][16][136]
  __shared__ __attribute__((aligned(16))) f16 obuf[32*136];
  __shared__ float wzg_s[64];
  __shared__ float wcs_s[4];
  const int tid = threadIdx.x;
  const int b = blockIdx.x >> 9, nb = blockIdx.x & 511;
  if (tid < 64) wzg_s[tid] = WZG[tid];
  if (tid < 4)  wcs_s[tid] = WCS[tid];

  const int l = tid & 63, w = tid >> 6;
  const int c = l & 15, q4 = l >> 4;
  const int h = w >> 1, qh = w & 1, m0 = qh*16;

  // ---- QK scores first (no LDS dependency; overlaps the z stream) ----
  const f16x8 aq = ld8(Q + ((size_t)b*16384 + (size_t)nb*32 + m0 + c)*128 + h*32 + q4*8);
  const long kbase = (long)b*16384 + (long)nb*32 - 48;   // OOB stays inside ws: finite garbage, masked
  f32x4 sc[8];
  #pragma unroll
  for (int nt = 0; nt < 8; nt++){
    const f16x8 bf = ld8(K + (kbase + nt*16 + c)*128 + h*32 + q4*8);
    f32x4 zz = {0.f,0.f,0.f,0.f};
    sc[nt] = MFMA16(aq, bf, zz);
  }

  // ---- z -> LN (colsum fixup) -> bias tile in LDS ----
  __syncthreads();   // wzg_s visible
  #pragma unroll
  for (int i = 0; i < 8; i++){
    const int p  = tid + i*512;
    const int qq = p >> 7, kk = p & 127;
    const float* zp = Z + ((((size_t)b*512 + nb)*32 + qq)*128 + kk)*16;
    const float4 z0 = *(const float4*)(zp);
    const float4 z1 = *(const float4*)(zp + 4);
    const float4 z2 = *(const float4*)(zp + 8);
    const float4 z3 = *(const float4*)(zp + 12);
    const float xs[16] = {z0.x,z0.y,z0.z,z0.w, z1.x,z1.y,z1.z,z1.w,
                          z2.x,z2.y,z2.z,z2.w, z3.x,z3.y,z3.z,z3.w};
    float sm = 0.f, sq = 0.f;
    #pragma unroll
    for (int cc = 0; cc < 16; cc++){ sm += xs[cc]; sq += xs[cc]*xs[cc]; }
    const float mean = sm*(1.f/16.f);
    const float var  = sq*(1.f/16.f) - mean*mean;
    const float rs   = rsqrtf(var + 1e-5f);
    #pragma unroll
    for (int hh = 0; hh < 4; hh++){
      float acc = 0.f;
      #pragma unroll
      for (int cc = 0; cc < 16; cc++) acc += xs[cc]*wzg_s[hh*16+cc];
      upb[(hh*32 + qq)*132 + kk] = (f16)((acc - mean*wcs_s[hh])*rs);
    }
  }
  __syncthreads();

  // ---- bias + mask + softmax ----
  #pragma unroll
  for (int nt = 0; nt < 8; nt++){
    const int key = nt*16 + c;
    const long kt = (long)nb*32 - 48 + key;
    const bool inv = (kt < 0) || (kt >= 16384);
    #pragma unroll
    for (int r = 0; r < 4; r++){
      const float v = sc[nt][r] + (float)upb[(h*32 + m0 + q4*4 + r)*132 + key];
      sc[nt][r] = inv ? -1e9f : v;
    }
  }
  #pragma unroll
  for (int r = 0; r < 4; r++){
    float mx = sc[0][r];
    #pragma unroll
    for (int nt = 1; nt < 8; nt++) mx = fmaxf(mx, sc[nt][r]);
    #pragma unroll
    for (int o = 8; o; o >>= 1) mx = fmaxf(mx, __shfl_xor(mx, o));
    float sum = 0.f;
    #pragma unroll
    for (int nt = 0; nt < 8; nt++){ const float e = __expf(sc[nt][r]-mx); sc[nt][r] = e; sum += e; }
    #pragma unroll
    for (int o = 8; o; o >>= 1) sum += __shfl_xor(sum, o);
    const float inv = 1.f/sum;
    #pragma unroll
    for (int nt = 0; nt < 8; nt++) sc[nt][r] *= inv;
  }
  __syncthreads();   // all bias reads done -> reuse upb as P
  #pragma unroll
  for (int nt = 0; nt < 8; nt++)
    #pragma unroll
    for (int r = 0; r < 4; r++)
      upb[(w*16 + q4*4 + r)*136 + nt*16 + c] = (f16)sc[nt][r];

  // ---- O = P @ V (V^T frags direct from global) ----
  const f16* vb = VT + ((long)b*128)*16384 + (long)nb*32 - 48;
  f32x4 o0 = {0.f,0.f,0.f,0.f}, o1 = {0.f,0.f,0.f,0.f};
  #pragma unroll
  for (int kc = 0; kc < 4; kc++){
    const f16x8 pa = *(const f16x8*)&upb[(w*16 + c)*136 + kc*32 + q4*8];
    const f16x8 v0 = ld8(vb + (long)(h*32 + c)*16384 + kc*32 + q4*8);
    const f16x8 v1 = ld8(vb + (long)(h*32 + 16 + c)*16384 + kc*32 + q4*8);
    o0 = MFMA16(pa, v0, o0);
    o1 = MFMA16(pa, v1, o1);
  }
  // stage o in LDS for the output projection
  #pragma unroll
  for (int r = 0; r < 4; r++){
    obuf[(m0 + q4*4 + r)*136 + h*32 + c]      = (f16)o0[r];
    obuf[(m0 + q4*4 + r)*136 + h*32 + 16 + c] = (f16)o1[r];
  }
  __syncthreads();

  // ---- out = gl*((g.o)@Wo) + gs*(t@Wb); wave w owns col-tile w*16 ----
  const int n0 = w*16;
  f16x8 bo[4];
  #pragma unroll
  for (int kc = 0; kc < 4; kc++) bo[kc] = ld8(Wot + (size_t)(n0 + c)*128 + kc*32 + q4*8);
  const size_t tok0 = (size_t)b*16384 + (size_t)nb*32;
  #pragma unroll
  for (int mt = 0; mt < 2; mt++){
    const size_t arow = tok0 + mt*16 + c;
    f32x4 d1 = {0,0,0,0}, d2 = {0,0,0,0};
    #pragma unroll
    for (int kc = 0; kc < 4; kc++){
      const f16x8 av = ld8(G + arow*128 + kc*32 + q4*8) *
                       *(const f16x8*)&obuf[(mt*16 + c)*136 + kc*32 + q4*8];
      d1 = MFMA16(av, bo[kc], d1);
    }
    #pragma unroll
    for (int kc = 0; kc < 8; kc++){
      const f16x8 at = ld8(T + arow*256 + kc*32 + q4*8);
      d2 = MFMA16(at, ld8(Wbt + (size_t)(n0 + c)*256 + kc*32 + q4*8), d2);
    }
    #pragma unroll
    for (int r = 0; r < 4; r++){
      const size_t row = tok0 + mt*16 + q4*4 + r;
      const float glv = (float)GL[row*128 + n0 + c];
      const float gsv = (float)GS[row*128 + n0 + c];
      out[row*128 + n0 + c] = glv*d1[r] + gsv*d2[r];
    }
  }
}

// ---------------------------------------------------------------------------
extern "C" void kernel_launch(void* const* d_in, const int* in_sizes, int n_in,
                              void* d_out, int out_size, void* d_ws, size_t ws_size,
                              hipStream_t stream)
{
  (void)in_sizes; (void)n_in; (void)out_size; (void)ws_size;
  const float* a        = (const float*)d_in[0];
  const float* s        = (const float*)d_in[1];
  const float* z        = (const float*)d_in[2];
  const float* apb_gamma= (const float*)d_in[3];
  const float* apb_Wg   = (const float*)d_in[4];
  const float* apb_bg   = (const float*)d_in[5];
  const float* apb_Wskip= (const float*)d_in[6];
  const float* Wq       = (const float*)d_in[7];
  const float* bq       = (const float*)d_in[8];
  const float* Wk       = (const float*)d_in[9];
  const float* Wv       = (const float*)d_in[10];
  const float* Wgate    = (const float*)d_in[11];
  const float* Wo       = (const float*)d_in[12];
  const float* gamma_z  = (const float*)d_in[13];
  const float* Wz       = (const float*)d_in[14];
  const float* Wsl      = (const float*)d_in[15];
  const float* bsl      = (const float*)d_in[16];
  const float* ct_gamma = (const float*)d_in[17];
  const float* ct_Wg    = (const float*)d_in[18];
  const float* ct_bg    = (const float*)d_in[19];
  const float* ct_Wskip = (const float*)d_in[20];
  const float* Wa1      = (const float*)d_in[21];
  const float* Wa2      = (const float*)d_in[22];
  const float* Wb       = (const float*)d_in[23];
  const float* Wss      = (const float*)d_in[24];
  const float* bss      = (const float*)d_in[25];

  f16* W0 = (f16*)d_ws;
  const size_t SL = (size_t)32768*128;
  f16* qv = W0 + 0*SL;
  f16* kv = W0 + 1*SL;
  f16* vt = W0 + 2*SL;
  f16* gv = W0 + 3*SL;
  f16* tv = W0 + 4*SL;   // 2 slots (32768 x 256)
  f16* gl = W0 + 6*SL;
  f16* gs = W0 + 7*SL;
  f16* wA  = W0 + 8*SL;
  f16* wC  = wA  + 256*128;
  f16* wQK = wC  + 256*128;
  f16* wVG = wQK + 256*128;
  f16* wSG = wVG + 256*128;
  f16* wAB = wSG + 256*128;
  f16* wO  = wAB + 512*128;
  f16* wBt = wO  + 128*128;
  float* wzg = (float*)(wBt + 128*256);
  float* Slv = wzg + 64;
  float* Ssv = Slv + 128;
  float* wcs = Ssv + 128;

  k_prep<<<dim3(64),256,0,stream>>>(apb_gamma,apb_Wg,apb_Wskip, ct_gamma,ct_Wg,ct_Wskip,
      Wq,Wk,Wv,Wgate, Wsl,Wss, Wa1,Wa2, Wo,Wb, gamma_z,Wz,
      wA,wC,wQK,wVG,wSG,wAB,wO,wBt,wzg,Slv,Ssv,wcs);
  k_pre<<<dim3(512),256,0,stream>>>(a,s, wA,wC,wQK,wVG,wSG,wAB,
      apb_bg,ct_bg,bq,bsl,bss,Slv,Ssv, qv,kv,vt,gv,tv,gl,gs);
  k_attn<<<dim3(1024),512,0,stream>>>(qv,kv,vt,z,wzg,wcs, gv,tv,gl,gs, wO,wBt,
      (float*)d_out);
}

// Round 6
// 568.109 us; speedup vs baseline: 1.0234x; 1.0234x over previous
//
#include <hip/hip_runtime.h>

typedef _Float16 f16;
typedef f16 f16x8 __attribute__((ext_vector_type(8)));
typedef f16 f16x4 __attribute__((ext_vector_type(4)));
typedef f16 f16x2 __attribute__((ext_vector_type(2)));
typedef float f32x4 __attribute__((ext_vector_type(4)));

#define MFMA16(a,b,c) __builtin_amdgcn_mfma_f32_16x16x32_f16((a),(b),(c),0,0,0)

static __device__ __forceinline__ f16x8 ld8(const f16* p){ return *(const f16x8*)p; }
static __device__ __forceinline__ float sigm(float x){ return 1.f/(1.f + __expf(-x)); }

// ---------------------------------------------------------------------------
// Weight prep: fold gammas, cast fp16, transpose to N-major (K contiguous).
// Extras: colsums of Wsl/Wss (raw-s gate un-normalization), gamma_z*Wz fused
// vector + its per-head colsum (z-LN fixup).
// ---------------------------------------------------------------------------
__global__ __launch_bounds__(256) void k_prep(
    const float* __restrict__ apb_gamma, const float* __restrict__ apb_Wg, const float* __restrict__ apb_Wskip,
    const float* __restrict__ ct_gamma,  const float* __restrict__ ct_Wg,  const float* __restrict__ ct_Wskip,
    const float* __restrict__ Wq, const float* __restrict__ Wk, const float* __restrict__ Wv, const float* __restrict__ Wgate,
    const float* __restrict__ Wsl, const float* __restrict__ Wss,
    const float* __restrict__ Wa1, const float* __restrict__ Wa2,
    const float* __restrict__ Wo, const float* __restrict__ Wb,
    const float* __restrict__ gamma_z, const float* __restrict__ Wz,
    f16* __restrict__ wA, f16* __restrict__ wC, f16* __restrict__ wQK, f16* __restrict__ wVG,
    f16* __restrict__ wSG, f16* __restrict__ wAB, f16* __restrict__ wO, f16* __restrict__ wBt,
    float* __restrict__ wzg, float* __restrict__ Slv, float* __restrict__ Ssv,
    float* __restrict__ wcs)
{
  const int t0 = blockIdx.x*256 + threadIdx.x;
  const int stride = gridDim.x*256;
  for (int i = t0; i < 256*128; i += stride){
    const int n = i >> 7, k = i & 127;
    const int m = n & 127;
    wA[i]  = (f16)(((n<128) ? apb_Wg[k*128+m] : apb_Wskip[k*128+m]) * apb_gamma[k]);
    wC[i]  = (f16)(((n<128) ? ct_Wg[k*128+m]  : ct_Wskip[k*128+m])  * ct_gamma[k]);
    wQK[i] = (f16)((n<128) ? Wq[k*128+m] : Wk[k*128+m]);
    wVG[i] = (f16)((n<128) ? Wv[k*128+m] : Wgate[k*128+m]);
    wSG[i] = (f16)((n<128) ? Wsl[k*128+m] : Wss[k*128+m]);
  }
  for (int i = t0; i < 512*128; i += stride){
    const int n = i >> 7, k = i & 127;
    wAB[i] = (f16)((n < 256) ? Wa1[k*256 + n] : Wa2[k*256 + (n-256)]);
  }
  for (int i = t0; i < 128*128; i += stride){
    const int n = i >> 7, k = i & 127;
    wO[i] = (f16)Wo[k*128+n];
  }
  for (int i = t0; i < 128*256; i += stride){
    const int n = i >> 8, k = i & 255;
    wBt[i] = (f16)Wb[k*128+n];
  }
  if (t0 < 64) wzg[t0] = gamma_z[t0 & 15] * Wz[(t0 & 15)*4 + (t0 >> 4)];
  if (t0 < 256){
    const int cc = t0 & 127;
    const float* Wp = (t0 >= 128) ? Wss : Wsl;
    float acc = 0.f;
    for (int k = 0; k < 128; k++) acc += Wp[k*128 + cc];
    if (t0 >= 128) Ssv[cc] = acc; else Slv[cc] = acc;
  }
  if (t0 < 4){
    float acc = 0.f;
    for (int cc = 0; cc < 16; cc++) acc += gamma_z[cc]*Wz[cc*4 + t0];
    wcs[t0] = acc;
  }
}

// ---------------------------------------------------------------------------
// Dedicated z->bias streaming kernel (pure BW). One thread per (b,nb,q,k):
// read 16 fp32 (64 B coalesced), LN via colsum fixup, 4 head dots, 4 f16 out.
// NO mask baked — masking is done explicitly in k_attn (determinism).
// Bias layout: [b*512+nb][h][q][k] f16.
// ---------------------------------------------------------------------------
__global__ __launch_bounds__(256) void k_zbias(
    const float* __restrict__ Z, const float* __restrict__ WZG, const float* __restrict__ WCS,
    f16* __restrict__ Bias)
{
  __shared__ float wzg_s[64];
  __shared__ float wcs_s[4];
  if (threadIdx.x < 64) wzg_s[threadIdx.x] = WZG[threadIdx.x];
  if (threadIdx.x < 4)  wcs_s[threadIdx.x] = WCS[threadIdx.x];
  __syncthreads();
  const int e = blockIdx.x*256 + threadIdx.x;     // 4.19M elements
  const int kk  = e & 127;
  const int qq  = (e >> 7) & 31;
  const int bnb = e >> 12;
  const float* zp = Z + (size_t)e*16;
  const float4 z0 = *(const float4*)(zp);
  const float4 z1 = *(const float4*)(zp + 4);
  const float4 z2 = *(const float4*)(zp + 8);
  const float4 z3 = *(const float4*)(zp + 12);
  const float xs[16] = {z0.x,z0.y,z0.z,z0.w, z1.x,z1.y,z1.z,z1.w,
                        z2.x,z2.y,z2.z,z2.w, z3.x,z3.y,z3.z,z3.w};
  float sm = 0.f, sq = 0.f;
  #pragma unroll
  for (int cc = 0; cc < 16; cc++){ sm += xs[cc]; sq += xs[cc]*xs[cc]; }
  const float mean = sm*(1.f/16.f);
  const float var  = sq*(1.f/16.f) - mean*mean;
  const float rs   = rsqrtf(var + 1e-5f);
  #pragma unroll
  for (int hh = 0; hh < 4; hh++){
    float acc = 0.f;
    #pragma unroll
    for (int cc = 0; cc < 16; cc++) acc += xs[cc]*wzg_s[hh*16+cc];
    Bias[((size_t)bnb*4 + hh)*4096 + qq*128 + kk] = (f16)((acc - mean*wcs_s[hh])*rs);
  }
}

// ---------------------------------------------------------------------------
// MEGA-FUSED pre-attention (round-4 verbatim, known-good numerics).
// 64 rows/block, 256 threads, 52 KB LDS -> 3 blocks/CU.
// ---------------------------------------------------------------------------
__global__ __launch_bounds__(256,3) void k_pre(
    const float* __restrict__ A, const float* __restrict__ S,
    const f16* __restrict__ wA, const f16* __restrict__ wC,
    const f16* __restrict__ wQK, const f16* __restrict__ wVG,
    const f16* __restrict__ wSG, const f16* __restrict__ wAB,
    const float* __restrict__ bgA, const float* __restrict__ bgC,
    const float* __restrict__ bq, const float* __restrict__ bsl, const float* __restrict__ bss,
    const float* __restrict__ Slv, const float* __restrict__ Ssv,
    f16* __restrict__ Qo, f16* __restrict__ Ko, f16* __restrict__ Vt, f16* __restrict__ Go,
    f16* __restrict__ T, f16* __restrict__ GL, f16* __restrict__ GS)
{
  __shared__ __attribute__((aligned(16))) f16 lsn[64*136];
  __shared__ __attribute__((aligned(16))) f16 lan[64*136];   // a_n, then a3
  __shared__ __attribute__((aligned(16))) f16 la1[64*136];
  __shared__ float lsm[64], lsd[64];
  const int tid = threadIdx.x;
  const size_t rbase = (size_t)blockIdx.x * 64;

  // ---- Phase 1: LayerNorm ----
  {
    const int row = tid >> 2, part = tid & 3;
    const size_t gr = rbase + row;
    {
      const float* sp = S + gr*128 + part*32;
      float v[32];
      #pragma unroll
      for (int j = 0; j < 8; j++){
        const float4 t4 = ((const float4*)sp)[j];
        v[j*4+0]=t4.x; v[j*4+1]=t4.y; v[j*4+2]=t4.z; v[j*4+3]=t4.w;
      }
      float sm = 0.f, sq = 0.f;
      #pragma unroll
      for (int j = 0; j < 32; j++){ sm += v[j]; sq += v[j]*v[j]; }
      sm += __shfl_xor(sm,1); sq += __shfl_xor(sq,1);
      sm += __shfl_xor(sm,2); sq += __shfl_xor(sq,2);
      const float mean = sm*(1.f/128.f);
      const float var  = sq*(1.f/128.f) - mean*mean;
      const float rstd = rsqrtf(var + 1e-5f);
      if (part == 0){ lsm[row] = mean; lsd[row] = (var + 1e-5f)*rstd; }
      #pragma unroll
      for (int j = 0; j < 4; j++){
        f16x8 o;
        #pragma unroll
        for (int e = 0; e < 8; e++) o[e] = (f16)((v[j*8+e]-mean)*rstd);
        *(f16x8*)&lsn[row*136 + part*32 + j*8] = o;
      }
    }
    {
      const float* ap = A + gr*128 + part*32;
      float v[32];
      #pragma unroll
      for (int j = 0; j < 8; j++){
        const float4 t4 = ((const float4*)ap)[j];
        v[j*4+0]=t4.x; v[j*4+1]=t4.y; v[j*4+2]=t4.z; v[j*4+3]=t4.w;
      }
      float sm = 0.f, sq = 0.f;
      #pragma unroll
      for (int j = 0; j < 32; j++){ sm += v[j]; sq += v[j]*v[j]; }
      sm += __shfl_xor(sm,1); sq += __shfl_xor(sq,1);
      sm += __shfl_xor(sm,2); sq += __shfl_xor(sq,2);
      const float mean = sm*(1.f/128.f);
      const float var  = sq*(1.f/128.f) - mean*mean;
      const float rstd = rsqrtf(var + 1e-5f);
      #pragma unroll
      for (int j = 0; j < 4; j++){
        f16x8 o;
        #pragma unroll
        for (int e = 0; e < 8; e++) o[e] = (f16)((v[j*8+e]-mean)*rstd);
        *(f16x8*)&lan[row*136 + part*32 + j*8] = o;
      }
    }
  }
  __syncthreads();

  const int l = tid & 63, w = tid >> 6;
  const int c = l & 15, q4 = l >> 4;

  // ---- Phase 2: dual adaLN, one job per col-tile (8 jobs) ----
  for (int jj = 0; jj < 2; jj++){
    const int n0 = (jj*4 + w)*16;
    const float bvA = bgA[n0 + c], bvC = bgC[n0 + c];
    f16x8 bA0[4], bA1[4], bC0[4], bC1[4];
    #pragma unroll
    for (int kc = 0; kc < 4; kc++){
      bA0[kc] = ld8(wA + (size_t)(n0 + c)*128 + kc*32 + q4*8);
      bA1[kc] = ld8(wA + (size_t)(128 + n0 + c)*128 + kc*32 + q4*8);
      bC0[kc] = ld8(wC + (size_t)(n0 + c)*128 + kc*32 + q4*8);
      bC1[kc] = ld8(wC + (size_t)(128 + n0 + c)*128 + kc*32 + q4*8);
    }
    for (int mi = 0; mi < 4; mi++){
      f32x4 dA0 = {0,0,0,0}, dA1 = {0,0,0,0}, dC0 = {0,0,0,0}, dC1 = {0,0,0,0};
      #pragma unroll
      for (int kc = 0; kc < 4; kc++){
        const f16x8 av = *(const f16x8*)&lsn[(mi*16 + c)*136 + kc*32 + q4*8];
        dA0 = MFMA16(av, bA0[kc], dA0);
        dA1 = MFMA16(av, bA1[kc], dA1);
        dC0 = MFMA16(av, bC0[kc], dC0);
        dC1 = MFMA16(av, bC1[kc], dC1);
      }
      #pragma unroll
      for (int r = 0; r < 4; r++){
        const int row = mi*16 + q4*4 + r;
        const float anv = (float)lan[row*136 + n0 + c];
        la1[row*136 + n0 + c] = (f16)(sigm(dA0[r] + bvA)*anv + dA1[r]);
        lan[row*136 + n0 + c] = (f16)(sigm(dC0[r] + bvC)*anv + dC1[r]);   // a3 overlays a_n
      }
    }
  }
  __syncthreads();

  // ---- Phase 3a: QKVG from a1 ----
  for (int jj = 0; jj < 2; jj++){
    const int n0 = (jj*4 + w)*16;
    f16x8 bQ[4], bK[4], bV[4], bG[4];
    #pragma unroll
    for (int kc = 0; kc < 4; kc++){
      bQ[kc] = ld8(wQK + (size_t)(n0 + c)*128 + kc*32 + q4*8);
      bK[kc] = ld8(wQK + (size_t)(128 + n0 + c)*128 + kc*32 + q4*8);
      bV[kc] = ld8(wVG + (size_t)(n0 + c)*128 + kc*32 + q4*8);
      bG[kc] = ld8(wVG + (size_t)(128 + n0 + c)*128 + kc*32 + q4*8);
    }
    const float bvq = bq[n0 + c];
    for (int mi = 0; mi < 4; mi++){
      f32x4 dQ = {0,0,0,0}, dK = {0,0,0,0}, dV = {0,0,0,0}, dG = {0,0,0,0};
      #pragma unroll
      for (int kc = 0; kc < 4; kc++){
        const f16x8 av = *(const f16x8*)&la1[(mi*16 + c)*136 + kc*32 + q4*8];
        dQ = MFMA16(av, bQ[kc], dQ);
        dK = MFMA16(av, bK[kc], dK);
        dV = MFMA16(av, bV[kc], dV);
        dG = MFMA16(av, bG[kc], dG);
      }
      #pragma unroll
      for (int r = 0; r < 4; r++){
        const size_t grow = rbase + mi*16 + q4*4 + r;
        Qo[grow*128 + n0 + c] = (f16)((dQ[r] + bvq)*0.17677669529663687f);
        Ko[grow*128 + n0 + c] = (f16)dK[r];
        Go[grow*128 + n0 + c] = (f16)sigm(dG[r]);
      }
      f16x4 vv;
      #pragma unroll
      for (int r = 0; r < 4; r++) vv[r] = (f16)dV[r];
      const int bidx = (int)(rbase >> 14);
      const int ntk  = (int)(rbase & 16383) + mi*16 + q4*4;
      *(f16x4*)(Vt + ((size_t)bidx*128 + n0 + c)*16384 + ntk) = vv;
    }
  }

  // ---- Phase 3b: transition from a3 (in lan) ----
  for (int jj = 0; jj < 4; jj++){
    const int n0t = (jj*4 + w)*16;
    f16x8 b1v[4], b2v[4];
    #pragma unroll
    for (int kc = 0; kc < 4; kc++){
      b1v[kc] = ld8(wAB + (size_t)(n0t + c)*128 + kc*32 + q4*8);
      b2v[kc] = ld8(wAB + (size_t)(256 + n0t + c)*128 + kc*32 + q4*8);
    }
    for (int mi = 0; mi < 4; mi++){
      f32x4 d0 = {0,0,0,0}, d1 = {0,0,0,0};
      #pragma unroll
      for (int kc = 0; kc < 4; kc++){
        const f16x8 av = *(const f16x8*)&lan[(mi*16 + c)*136 + kc*32 + q4*8];
        d0 = MFMA16(av, b1v[kc], d0);
        d1 = MFMA16(av, b2v[kc], d1);
      }
      #pragma unroll
      for (int r = 0; r < 4; r++){
        const size_t grow = rbase + mi*16 + q4*4 + r;
        const float u = d0[r];
        T[grow*256 + n0t + c] = (f16)((u*sigm(u))*d1[r]);
      }
    }
  }

  // ---- Phase 3c: gates from sn (un-normalization trick) ----
  for (int jj = 0; jj < 2; jj++){
    const int n0 = (jj*4 + w)*16;
    f16x8 b0[4], b1[4];
    #pragma unroll
    for (int kc = 0; kc < 4; kc++){
      b0[kc] = ld8(wSG + (size_t)(n0 + c)*128 + kc*32 + q4*8);
      b1[kc] = ld8(wSG + (size_t)(128 + n0 + c)*128 + kc*32 + q4*8);
    }
    const float slc = Slv[n0 + c], ssc = Ssv[n0 + c];
    const float bl = bsl[n0 + c],  bs2 = bss[n0 + c];
    for (int mi = 0; mi < 4; mi++){
      f32x4 d0 = {0,0,0,0}, d1 = {0,0,0,0};
      #pragma unroll
      for (int kc = 0; kc < 4; kc++){
        const f16x8 av = *(const f16x8*)&lsn[(mi*16 + c)*136 + kc*32 + q4*8];
        d0 = MFMA16(av, b0[kc], d0);
        d1 = MFMA16(av, b1[kc], d1);
      }
      #pragma unroll
      for (int r = 0; r < 4; r++){
        const int row = mi*16 + q4*4 + r;
        const size_t grow = rbase + row;
        const float mn = lsm[row], sd = lsd[row];
        GL[grow*128 + n0 + c] = (f16)sigm(d0[r]*sd + mn*slc + bl);
        GS[grow*128 + n0 + c] = (f16)sigm(d1[r]*sd + mn*ssc + bs2);
      }
    }
  }
}

// ---------------------------------------------------------------------------
// Attention + output projection. Bias precomputed by k_zbias. ALL global
// reads are clamped in-range (no OOB garbage anywhere); masking is explicit
// fp32 replacement with -1e9 (masked P becomes exactly 0).
// ---------------------------------------------------------------------------
__global__ __launch_bounds__(512,2) void k_attn(const f16* __restrict__ Q, const f16* __restrict__ K,
    const f16* __restrict__ VT, const f16* __restrict__ Bias,
    const f16* __restrict__ G, const f16* __restrict__ T,
    const f16* __restrict__ GL, const f16* __restrict__ GS,
    const f16* __restrict__ Wot, const f16* __restrict__ Wbt,
    float* __restrict__ out)
{
  __shared__ __attribute__((aligned(16))) f16 upb[17408];   // bias[4][32][136] then P[8][16][136]
  __shared__ __attribute__((aligned(16))) f16 obuf[32*136];
  const int tid = threadIdx.x;
  const int b = blockIdx.x >> 9, nb = blockIdx.x & 511;

  const int l = tid & 63, w = tid >> 6;
  const int c = l & 15, q4 = l >> 4;
  const int h = w >> 1, qh = w & 1, m0 = qh*16;

  // ---- QK scores (global frags, clamped addresses; overlaps bias copy) ----
  const f16x8 aq = ld8(Q + ((size_t)b*16384 + (size_t)nb*32 + m0 + c)*128 + h*32 + q4*8);
  const int wbase = nb*32 - 48;
  f32x4 sc[8];
  #pragma unroll
  for (int nt = 0; nt < 8; nt++){
    int kt = wbase + nt*16 + c;
    kt = (kt < 0) ? 0 : ((kt > 16383) ? 16383 : kt);
    const f16x8 bf = ld8(K + ((size_t)b*16384 + kt)*128 + h*32 + q4*8);
    f32x4 zz = {0.f,0.f,0.f,0.f};
    sc[nt] = MFMA16(aq, bf, zz);
  }

  // ---- bias tile -> LDS (coalesced copy) ----
  {
    const f16* bp = Bias + (size_t)blockIdx.x*16384;
    #pragma unroll
    for (int i = 0; i < 4; i++){
      const int idx = tid + i*512;       // 2048 chunks of 8
      const int hq  = idx >> 4;          // h*32+q
      const int kc8 = idx & 15;
      *(f16x8*)&upb[hq*136 + kc8*8] = ld8(bp + hq*128 + kc8*8);
    }
  }
  __syncthreads();

  // ---- bias + explicit mask + softmax ----
  #pragma unroll
  for (int nt = 0; nt < 8; nt++){
    const int key = nt*16 + c;
    const int kt = wbase + key;
    const bool inv = (kt < 0) || (kt >= 16384);
    #pragma unroll
    for (int r = 0; r < 4; r++){
      const float v = sc[nt][r] + (float)upb[(h*32 + m0 + q4*4 + r)*136 + key];
      sc[nt][r] = inv ? -1e9f : v;
    }
  }
  #pragma unroll
  for (int r = 0; r < 4; r++){
    float mx = sc[0][r];
    #pragma unroll
    for (int nt = 1; nt < 8; nt++) mx = fmaxf(mx, sc[nt][r]);
    #pragma unroll
    for (int o = 8; o; o >>= 1) mx = fmaxf(mx, __shfl_xor(mx, o));
    float sum = 0.f;
    #pragma unroll
    for (int nt = 0; nt < 8; nt++){ const float e = __expf(sc[nt][r]-mx); sc[nt][r] = e; sum += e; }
    #pragma unroll
    for (int o = 8; o; o >>= 1) sum += __shfl_xor(sum, o);
    const float inv = 1.f/sum;
    #pragma unroll
    for (int nt = 0; nt < 8; nt++) sc[nt][r] *= inv;
  }
  __syncthreads();   // all bias reads done -> reuse upb as P
  #pragma unroll
  for (int nt = 0; nt < 8; nt++)
    #pragma unroll
    for (int r = 0; r < 4; r++)
      upb[(w*16 + q4*4 + r)*136 + nt*16 + c] = (f16)sc[nt][r];

  // ---- O = P @ V (V^T frags, clamped token windows; masked P = 0) ----
  f32x4 o0 = {0.f,0.f,0.f,0.f}, o1 = {0.f,0.f,0.f,0.f};
  #pragma unroll
  for (int kc = 0; kc < 4; kc++){
    int t0v = wbase + kc*32 + q4*8;
    t0v = (t0v < 0) ? 0 : ((t0v > 16376) ? 16376 : t0v);
    const f16x8 pa = *(const f16x8*)&upb[(w*16 + c)*136 + kc*32 + q4*8];
    const f16x8 v0 = ld8(VT + ((size_t)b*128 + h*32 + c)*16384 + t0v);
    const f16x8 v1 = ld8(VT + ((size_t)b*128 + h*32 + 16 + c)*16384 + t0v);
    o0 = MFMA16(pa, v0, o0);
    o1 = MFMA16(pa, v1, o1);
  }
  #pragma unroll
  for (int r = 0; r < 4; r++){
    obuf[(m0 + q4*4 + r)*136 + h*32 + c]      = (f16)o0[r];
    obuf[(m0 + q4*4 + r)*136 + h*32 + 16 + c] = (f16)o1[r];
  }
  __syncthreads();

  // ---- out = gl*((g.o)@Wo) + gs*(t@Wb); wave w owns col-tile w*16 ----
  const int n0 = w*16;
  f16x8 bo[4];
  #pragma unroll
  for (int kc = 0; kc < 4; kc++) bo[kc] = ld8(Wot + (size_t)(n0 + c)*128 + kc*32 + q4*8);
  const size_t tok0 = (size_t)b*16384 + (size_t)nb*32;
  #pragma unroll
  for (int mt = 0; mt < 2; mt++){
    const size_t arow = tok0 + mt*16 + c;
    f32x4 d1 = {0,0,0,0}, d2 = {0,0,0,0};
    #pragma unroll
    for (int kc = 0; kc < 4; kc++){
      const f16x8 av = ld8(G + arow*128 + kc*32 + q4*8) *
                       *(const f16x8*)&obuf[(mt*16 + c)*136 + kc*32 + q4*8];
      d1 = MFMA16(av, bo[kc], d1);
    }
    #pragma unroll
    for (int kc = 0; kc < 8; kc++){
      const f16x8 at = ld8(T + arow*256 + kc*32 + q4*8);
      d2 = MFMA16(at, ld8(Wbt + (size_t)(n0 + c)*256 + kc*32 + q4*8), d2);
    }
    #pragma unroll
    for (int r = 0; r < 4; r++){
      const size_t row = tok0 + mt*16 + q4*4 + r;
      const float glv = (float)GL[row*128 + n0 + c];
      const float gsv = (float)GS[row*128 + n0 + c];
      out[row*128 + n0 + c] = glv*d1[r] + gsv*d2[r];
    }
  }
}

// ---------------------------------------------------------------------------
extern "C" void kernel_launch(void* const* d_in, const int* in_sizes, int n_in,
                              void* d_out, int out_size, void* d_ws, size_t ws_size,
                              hipStream_t stream)
{
  (void)in_sizes; (void)n_in; (void)out_size; (void)ws_size;
  const float* a        = (const float*)d_in[0];
  const float* s        = (const float*)d_in[1];
  const float* z        = (const float*)d_in[2];
  const float* apb_gamma= (const float*)d_in[3];
  const float* apb_Wg   = (const float*)d_in[4];
  const float* apb_bg   = (const float*)d_in[5];
  const float* apb_Wskip= (const float*)d_in[6];
  const float* Wq       = (const float*)d_in[7];
  const float* bq       = (const float*)d_in[8];
  const float* Wk       = (const float*)d_in[9];
  const float* Wv       = (const float*)d_in[10];
  const float* Wgate    = (const float*)d_in[11];
  const float* Wo       = (const float*)d_in[12];
  const float* gamma_z  = (const float*)d_in[13];
  const float* Wz       = (const float*)d_in[14];
  const float* Wsl      = (const float*)d_in[15];
  const float* bsl      = (const float*)d_in[16];
  const float* ct_gamma = (const float*)d_in[17];
  const float* ct_Wg    = (const float*)d_in[18];
  const float* ct_bg    = (const float*)d_in[19];
  const float* ct_Wskip = (const float*)d_in[20];
  const float* Wa1      = (const float*)d_in[21];
  const float* Wa2      = (const float*)d_in[22];
  const float* Wb       = (const float*)d_in[23];
  const float* Wss      = (const float*)d_in[24];
  const float* bss      = (const float*)d_in[25];

  f16* W0 = (f16*)d_ws;
  const size_t SL = (size_t)32768*128;
  f16* qv = W0 + 0*SL;
  f16* kv = W0 + 1*SL;
  f16* vt = W0 + 2*SL;
  f16* gv = W0 + 3*SL;
  f16* tv = W0 + 4*SL;    // 2 slots (32768 x 256)
  f16* gl = W0 + 6*SL;
  f16* gs = W0 + 7*SL;
  f16* bias = W0 + 8*SL;  // 4 slots (2*512*4*32*128 f16 = 33.5 MB)
  f16* wA  = W0 + 12*SL;
  f16* wC  = wA  + 256*128;
  f16* wQK = wC  + 256*128;
  f16* wVG = wQK + 256*128;
  f16* wSG = wVG + 256*128;
  f16* wAB = wSG + 256*128;
  f16* wO  = wAB + 512*128;
  f16* wBt = wO  + 128*128;
  float* wzg = (float*)(wBt + 128*256);
  float* Slv = wzg + 64;
  float* Ssv = Slv + 128;
  float* wcs = Ssv + 128;

  k_prep<<<dim3(64),256,0,stream>>>(apb_gamma,apb_Wg,apb_Wskip, ct_gamma,ct_Wg,ct_Wskip,
      Wq,Wk,Wv,Wgate, Wsl,Wss, Wa1,Wa2, Wo,Wb, gamma_z,Wz,
      wA,wC,wQK,wVG,wSG,wAB,wO,wBt,wzg,Slv,Ssv,wcs);
  k_zbias<<<dim3(16384),256,0,stream>>>(z,wzg,wcs,bias);
  k_pre<<<dim3(512),256,0,stream>>>(a,s, wA,wC,wQK,wVG,wSG,wAB,
      apb_bg,ct_bg,bq,bsl,bss,Slv,Ssv, qv,kv,vt,gv,tv,gl,gs);
  k_attn<<<dim3(1024),512,0,stream>>>(qv,kv,vt,bias, gv,tv,gl,gs, wO,wBt,
      (float*)d_out);
}